// Round 10
// baseline (651.233 us; speedup 1.0000x reference)
//
#include <hip/hip_runtime.h>
#include <hip/hip_bf16.h>

#define Bx 256
#define Tx 512
#define Ex 768
#define Hx 256
#define Gx 1024
#define Vx 7987

typedef unsigned short u16;
typedef unsigned int u32;
typedef __bf16 bf16;
typedef bf16 bf16x8 __attribute__((ext_vector_type(8)));
typedef u16 u16x8 __attribute__((ext_vector_type(8)));
typedef float f32x4 __attribute__((ext_vector_type(4)));
typedef int i32x4 __attribute__((ext_vector_type(4)));

__device__ __forceinline__ u16 f2bf(float f) {
  union { float f; u32 u; } x; x.f = f;
  u32 r = x.u + 0x7fffu + ((x.u >> 16) & 1u);
  return (u16)(r >> 16);
}
__device__ __forceinline__ float bf2f(u16 b) {
  union { u32 u; float f; } x; x.u = ((u32)b) << 16;
  return x.f;
}
__device__ __forceinline__ void gload16(const void* g, void* l) {
  __builtin_amdgcn_global_load_lds((const __attribute__((address_space(1))) u32*)g,
                                   (__attribute__((address_space(3))) u32*)l, 16, 0, 0);
}
__device__ __forceinline__ float sigf(float x) {
  return __builtin_amdgcn_rcpf(1.f + __builtin_amdgcn_exp2f(x * -1.442695041f));
}
// barrier draining LDS ops only; global loads stay in flight
__device__ __forceinline__ void bar_ds() {
  __builtin_amdgcn_sched_barrier(0);
  asm volatile("s_waitcnt lgkmcnt(0)" ::: "memory");
  __builtin_amdgcn_s_barrier();
  __builtin_amdgcn_sched_barrier(0);
}
#define WAITV(N) { asm volatile("s_waitcnt vmcnt(" #N ")"); __builtin_amdgcn_sched_barrier(0); }

__device__ __forceinline__ void gld2(int2& d, const char* base, u32 voff) {
  asm volatile("global_load_dwordx2 %0, %1, %2" : "=&v"(d) : "v"(voff), "s"(base));
}
// i8 MFMA, K=64: A = h (VGPR), B = weights pinned in AGPR
__device__ __forceinline__ void mfma_i8(i32x4& d, i32x4 a, i32x4 b) {
  asm volatile("v_mfma_i32_16x16x64_i8 %0, %1, %2, %0" : "+v"(d) : "v"(a), "a"(b));
}

// ---------------- conversion / packing kernels ----------------

__global__ void k_cvt(const float* __restrict__ src, u16* __restrict__ dst, int n) {
  int i = blockIdx.x * blockDim.x + threadIdx.x;
  int st = gridDim.x * blockDim.x;
  for (; i < n; i += st) dst[i] = f2bf(src[i]);
}

__global__ void k_bias(const float* __restrict__ bihf, const float* __restrict__ bhhf,
                       const float* __restrict__ bihb, const float* __restrict__ bhhb,
                       float* __restrict__ bcat) {
  int i = blockIdx.x * blockDim.x + threadIdx.x;
  if (i < Gx) { bcat[i] = bihf[i] + bhhf[i]; bcat[Gx + i] = bihb[i] + bhhb[i]; }
}

// per-output-row absmax scale: s[row] = max|w_hh[row,:]| / 127
__global__ void k_scales(const float* __restrict__ wf, const float* __restrict__ wb,
                         float* __restrict__ s) {
  int row = blockIdx.x;  // 0..2047 (dir*1024 + n)
  const float* w = (row < Gx) ? (wf + (size_t)row * Hx) : (wb + (size_t)(row - Gx) * Hx);
  int l = threadIdx.x;
  float m = 0.f;
  for (int j = l; j < Hx; j += 64) m = fmaxf(m, fabsf(w[j]));
#pragma unroll
  for (int off = 32; off; off >>= 1) m = fmaxf(m, __shfl_down(m, off));
  if (l == 0) s[row] = fmaxf(m, 1e-20f) * (1.f / 127.f);
}

// pack w_hh -> i8 fragment-linear for v_mfma_i32_16x16x64_i8 B-operand:
// pk[(((dir*4+kc)*64 + nb)*64 + lane)*16 + j] = q(w[dir][n=nb*16+(lane&15)][k=kc*64+(lane>>4)*16+j])
__global__ void k_pack_i8(const float* __restrict__ wf, const float* __restrict__ wb,
                          const float* __restrict__ s, char* __restrict__ pk) {
  int i = blockIdx.x * 256 + threadIdx.x;  // 32768 packers x 16 B
  int lane = i & 63, nb = (i >> 6) & 63, kc = (i >> 12) & 3, dir = (i >> 14) & 1;
  int n = nb * 16 + (lane & 15);
  int k0 = kc * 64 + ((lane >> 4) << 4);
  const float* w = dir ? wb : wf;
  float inv = 1.f / s[dir * Gx + n];
  int dw[4];
#pragma unroll
  for (int d4 = 0; d4 < 4; ++d4) {
    int v = 0;
#pragma unroll
    for (int j = 0; j < 4; ++j) {
      int q = (int)rintf(w[(size_t)n * Hx + k0 + d4 * 4 + j] * inv);
      v |= (q & 255) << (8 * j);
    }
    dw[d4] = v;
  }
  *(int4*)(pk + (size_t)i * 16) = make_int4(dw[0], dw[1], dw[2], dw[3]);
}

// ---------------- vocab projection GEMM (runs ONCE, bf16) ----------------
// vp[(tok*2 + dir)*1024 + (w*16 + u)*8 + g*2 + fc]
__global__ __launch_bounds__(256) void k_vproj(
    const u16* __restrict__ embbf, const u16* __restrict__ wih,
    const float* __restrict__ bcat, u16* __restrict__ vp) {
  __shared__ u16 sA[128 * 64];
  __shared__ u16 sB[128 * 64];
  const int tid = threadIdx.x;
  const int l = tid & 63, w = tid >> 6;
  const int bx = blockIdx.x & 15, by = blockIdx.x >> 4;  // by: 0..62
  const int wm = w >> 1, wn = w & 1;
  const int lr = l >> 3, lc = l & 7;

  f32x4 acc[4][4];
#pragma unroll
  for (int a = 0; a < 4; ++a)
#pragma unroll
    for (int b = 0; b < 4; ++b) acc[a][b] = f32x4{0.f, 0.f, 0.f, 0.f};

  size_t asrc[4], bsrc[4];
#pragma unroll
  for (int j = 0; j < 4; ++j) {
    int row = j * 32 + w * 8 + lr;
    int m = by * 128 + row;
    int er = (m < Vx) ? m : 0;
    asrc[j] = (size_t)er * (Ex * 2) + (size_t)((lc * 16) ^ ((row & 7) << 4));
    bsrc[j] = (size_t)(bx * 128 + row) * (Ex * 2) + (size_t)((lc * 16) ^ ((row & 7) << 4));
  }

  for (int kt = 0; kt < 12; ++kt) {
    const char* ebase = (const char*)embbf + (size_t)kt * 128;
    const char* wbase = (const char*)wih + (size_t)kt * 128;
#pragma unroll
    for (int j = 0; j < 4; ++j) {
      gload16(ebase + asrc[j], (char*)sA + (j * 32 + w * 8) * 128);
      gload16(wbase + bsrc[j], (char*)sB + (j * 32 + w * 8) * 128);
    }
    __syncthreads();
#pragma unroll
    for (int kk = 0; kk < 2; ++kk) {
      int kb = kk * 64 + ((l >> 4) * 16);
      bf16x8 av[4], bv[4];
#pragma unroll
      for (int f = 0; f < 4; ++f) {
        int r = wm * 64 + f * 16 + (l & 15);
        av[f] = *(const bf16x8*)((const char*)sA + r * 128 + (kb ^ ((r & 7) << 4)));
      }
#pragma unroll
      for (int f = 0; f < 4; ++f) {
        int n = wn * 64 + f * 16 + (l & 15);
        bv[f] = *(const bf16x8*)((const char*)sB + n * 128 + (kb ^ ((n & 7) << 4)));
      }
#pragma unroll
      for (int fm = 0; fm < 4; ++fm)
#pragma unroll
        for (int fn = 0; fn < 4; ++fn)
          acc[fm][fn] = __builtin_amdgcn_mfma_f32_16x16x32_bf16(av[fm], bv[fn], acc[fm][fn], 0, 0, 0);
    }
    __syncthreads();
  }
#pragma unroll
  for (int fn = 0; fn < 4; ++fn) {
    int col = bx * 128 + wn * 64 + fn * 16 + (l & 15);
    int dirc = col >> 10, c10 = col & 1023;
    int gq = c10 >> 8, wq = (c10 >> 5) & 7, fcq = (c10 >> 4) & 1, uq = c10 & 15;
    int pos = (wq * 16 + uq) * 8 + gq * 2 + fcq;
    float bias = bcat[col];
#pragma unroll
    for (int fm = 0; fm < 4; ++fm) {
      int m0 = by * 128 + wm * 64 + fm * 16 + ((l >> 4) << 2);
#pragma unroll
      for (int r = 0; r < 4; ++r)
        vp[((size_t)(m0 + r) * 2 + dirc) * 1024 + pos] = f2bf(acc[fm][fn][r] + bias);
    }
  }
}

// ---------------- vp -> i8 quantize, IN PLACE (race-free chunked) ----------------
// Block b owns rows [b*8, b*8+8) = bytes [b*16384, +16KB). Each of 8 waves reads
// its row (2KB bf16) to regs, block syncs, then writes 1KB i8 into the chunk's
// first half: vpq row r at (r>>3)*16384 + (r&7)*1024. Scale -> scg[row].
__global__ __launch_bounds__(512) void k_vq(u16* __restrict__ vp, float* __restrict__ scg) {
  const int tid = threadIdx.x;
  const int l = tid & 63;
  int row = blockIdx.x * 8 + (tid >> 6);
  bool valid = row < 2 * Vx;
  int rr = valid ? row : 2 * Vx - 1;
  const u16* src = vp + (size_t)rr * 1024;
  float v[16];
  float m = 0.f;
#pragma unroll
  for (int j = 0; j < 16; ++j) {
    v[j] = bf2f(src[l * 16 + j]);
    m = fmaxf(m, fabsf(v[j]));
  }
#pragma unroll
  for (int off = 32; off; off >>= 1) m = fmaxf(m, __shfl_xor(m, off));
  float sc = fmaxf(m, 1e-20f) * (1.f / 127.f);
  float inv = 1.f / sc;
  if (valid && l == 0) scg[row] = sc;
  __syncthreads();  // all reads of the 16KB chunk done before any write
  if (valid) {
    int dw[4];
#pragma unroll
    for (int d4 = 0; d4 < 4; ++d4) {
      int wv = 0;
#pragma unroll
      for (int j = 0; j < 4; ++j) {
        int qv = (int)rintf(v[d4 * 4 + j] * inv);
        wv |= (qv & 255) << (8 * j);
      }
      dw[d4] = wv;
    }
    char* dst = (char*)vp + (size_t)blockIdx.x * 16384 + (size_t)(row & 7) * 1024;
    *(int4*)(dst + l * 16) = make_int4(dw[0], dw[1], dw[2], dw[3]);
  }
}

// ---------------- recurrence: ONE launch, all 512 steps ----------------
// 256 blocks = 2 dirs x 128 slices (2 rows each). 8 waves/block.
// w_hh AGPR-resident (i8). h: replica frag-linear LDS, dbuf: M-row p=4q+m holds
// real row (p>>2)&1 -> every lane's acc[..][0] is its own row (q&1), no rotation.
// x-proj: i8 vpq gather 8B/lane + per-(tok,dir) scale from LDS table.
// Pipeline: ONE WAITV(0) per step-pair (counting-proof), loads issued at pair top.
#define STEPI(T, RB, WB, XC, SC) {                                            \
  i32x4 acc[8];                                                               \
  _Pragma("unroll") for (int nt = 0; nt < 8; ++nt) acc[nt] = i32x4{0, 0, 0, 0}; \
  _Pragma("unroll") for (int kc = 0; kc < 4; ++kc) {                          \
    i32x4 a = *(const i32x4*)((RB) + kc * 1024 + aoff);                       \
    _Pragma("unroll") for (int nt = 0; nt < 8; ++nt)                          \
      mfma_i8(acc[nt], a, wres[kc][nt]);                                      \
  }                                                                           \
  asm volatile("s_nop 7\n\ts_nop 7");                                         \
  float ga[2][4];                                                             \
  _Pragma("unroll") for (int fc = 0; fc < 2; ++fc)                            \
    _Pragma("unroll") for (int g = 0; g < 4; ++g) {                           \
      int j = g * 2 + fc;                                                     \
      int wd = (j < 4) ? (XC).x : (XC).y;                                     \
      float xval = (float)((wd << (24 - 8 * (j & 3))) >> 24) * (SC);          \
      ga[fc][g] = (float)acc[j][0] * qs[j] + xval;                            \
    }                                                                         \
  _Pragma("unroll") for (int fc = 0; fc < 2; ++fc) {                          \
    float si = sigf(ga[fc][0]);                                               \
    float sf = sigf(ga[fc][1]);                                               \
    float tv = 2.f * sigf(2.f * ga[fc][2]) - 1.f;                             \
    float so = sigf(ga[fc][3]);                                               \
    float cn = sf * creg[fc] + si * tv;                                       \
    float hn = so * (2.f * sigf(2.f * cn) - 1.f);                             \
    creg[fc] = cn;                                                            \
    if ((T) == tgt && q < 2)                                                  \
      gath[(size_t)(b0 + (q & 1)) * 512 + dir * 256 + w * 32 + fc * 16 + c] = hn; \
    int qh = (int)rintf(hn * 127.f);                                          \
    _Pragma("unroll") for (int m = 0; m < 4; ++m)                             \
      *((WB) + wb_base + fc * 256 + m * 16) = (char)qh;                       \
  }                                                                           \
  bar_ds();                                                                   \
}

__global__ __launch_bounds__(512, 2) void k_rnn(
    const char* __restrict__ wq, const float* __restrict__ wsc,
    const char* __restrict__ vpq, const float* __restrict__ scg,
    const int* __restrict__ input, const int* __restrict__ target,
    float* __restrict__ gath) {
  __shared__ __align__(16) char shd[2][4096];  // h i8 replica frag-linear, dbuf
  __shared__ int stok[1024];                   // tokens [2 rows][512 t]
  __shared__ float ssc[Vx];                    // per-token scale (own dir)
  const int tid = threadIdx.x;
  const int l = tid & 63, w = tid >> 6;
  const int q = l >> 4, c = l & 15;
  const int dir = blockIdx.x >> 7, slice = blockIdx.x & 127;
  const int b0 = slice * 2;
  const char* wqd = wq + (size_t)dir * 262144;

  // all w_hh -> AGPR: 4 kc x 8 nt x 16 B = 512 B/lane = 128 AGPRs
  i32x4 wres[4][8];
#pragma unroll
  for (int kc = 0; kc < 4; ++kc)
#pragma unroll
    for (int nt = 0; nt < 8; ++nt) {
      int nb = (nt >> 1) * 16 + w * 2 + (nt & 1);
      wres[kc][nt] = *(const i32x4*)(wqd + ((size_t)(kc * 64 + nb) * 64 + l) * 16);
    }
  float qs[8];
#pragma unroll
  for (int nt = 0; nt < 8; ++nt)
    qs[nt] = wsc[dir * Gx + (nt >> 1) * 256 + w * 32 + (nt & 1) * 16 + c] * (1.f / 127.f);

  // tokens + scale table -> LDS; zero both h buffers
  for (int i = tid; i < 1024; i += 512)
    stok[i] = input[(b0 + (i >> 9)) * Tx + (i & 511)];
  for (int i = tid; i < Vx; i += 512) ssc[i] = scg[i * 2 + dir];
  for (int i = tid; i < 2048; i += 512) ((int*)shd)[i] = 0;

  float creg[2] = {0.f, 0.f};
  const int tgt = target[b0 + (q & 1)];
  const u32 go2 = (u32)((w * 16 + c) * 8);

  const int aoff = (q << 8) + (c << 4);  // A-frag read: [kc][q][M-row=c][16B]
  // h write: p = 4q+m; off = (w>>1)*1024 + ((w&1)*2+fc)*256 + p*16 + c
  const int wb_base = (w >> 1) * 1024 + (w & 1) * 512 + (q << 6) + c;
  const char* rb0 = &shd[0][0];
  const char* rb1 = &shd[1][0];
  char* wb0 = &shd[0][0];
  char* wb1 = &shd[1][0];

  __syncthreads();
  asm volatile("s_waitcnt vmcnt(0)" ::: "memory");
  __builtin_amdgcn_sched_barrier(0);

  // prologue: tokens t=0,1; scales; issue both loads
  int tk0 = stok[(q & 1) * 512 + 0];
  int tk1 = stok[(q & 1) * 512 + 1];
  float scA = ssc[tk0], scB = ssc[tk1];
  int2 xvA, xvB;
  {
    u32 rA = (u32)(tk0 * 2 + dir), rB = (u32)(tk1 * 2 + dir);
    gld2(xvA, vpq, ((rA >> 3) << 14) + ((rA & 7) << 10) + go2);
    gld2(xvB, vpq, ((rB >> 3) << 14) + ((rB & 7) << 10) + go2);
  }

#pragma unroll 1
  for (int t = 0; t < Tx; t += 2) {
    WAITV(0);  // xvA(t), xvB(t+1) landed; ALL other VMEM drained (counting-proof)
    int2 xcA = xvA, xcB = xvB;
    float cA = scA, cB = scB;
    int ta = stok[(q & 1) * 512 + ((t + 2 < Tx) ? t + 2 : Tx - 1)];
    int tb = stok[(q & 1) * 512 + ((t + 3 < Tx) ? t + 3 : Tx - 1)];
    scA = ssc[ta];
    scB = ssc[tb];
    {
      u32 rA = (u32)(ta * 2 + dir), rB = (u32)(tb * 2 + dir);
      gld2(xvA, vpq, ((rA >> 3) << 14) + ((rA & 7) << 10) + go2);  // full-pair window
      gld2(xvB, vpq, ((rB >> 3) << 14) + ((rB & 7) << 10) + go2);
    }
    STEPI(t, rb0, wb1, xcA, cA);
    STEPI(t + 1, rb1, wb0, xcB, cB);
  }
}

// ---------------- output head ----------------
__global__ void k_out(const float* __restrict__ gath, const float* __restrict__ wout,
                      const float* __restrict__ bout, float* __restrict__ out) {
  int b = blockIdx.x, l = threadIdx.x;
  float s = 0.f;
  for (int j = l; j < 512; j += 64) s += gath[(size_t)b * 512 + j] * wout[j];
#pragma unroll
  for (int off = 32; off; off >>= 1) s += __shfl_down(s, off);
  if (l == 0) out[b] = 1.f / (1.f + __expf(-(s + bout[0])));
}

extern "C" void kernel_launch(void* const* d_in, const int* in_sizes, int n_in,
                              void* d_out, int out_size, void* d_ws, size_t ws_size,
                              hipStream_t stream) {
  const int* input = (const int*)d_in[0];
  const int* target = (const int*)d_in[1];
  const float* emb  = (const float*)d_in[3];
  const float* wihf = (const float*)d_in[4];
  const float* whhf = (const float*)d_in[5];
  const float* bihf = (const float*)d_in[6];
  const float* bhhf = (const float*)d_in[7];
  const float* wihb = (const float*)d_in[8];
  const float* whhb = (const float*)d_in[9];
  const float* bihb = (const float*)d_in[10];
  const float* bhhb = (const float*)d_in[11];
  const float* wout = (const float*)d_in[12];
  const float* bout = (const float*)d_in[13];
  float* out = (float*)d_out;

  char* ws = (char*)d_ws;
  u16* embbf  = (u16*)(ws + 0);          // 12,268,032 B
  u16* wih    = (u16*)(ws + 12268032);   //  3,145,728 B
  char* wq    = (char*)(ws + 15413760);  //    524,288 B  i8 packed w_hh
  float* wsc  = (float*)(ws + 15938048); //      8,192 B  per-row scales
  float* bcat = (float*)(ws + 15946240); //      8,192 B
  float* gath = (float*)(ws + 15954432); //    524,288 B
  u16* vp     = (u16*)(ws + 16478720);   // 33,030,144 B  bf16 -> quantized in place
  float* scg  = (float*)(ws + 49508864); //     65,536 B  per-(tok,dir) vp scales

  k_cvt<<<1024, 256, 0, stream>>>(emb, embbf, Vx * Ex);
  k_cvt<<<512, 256, 0, stream>>>(wihf, wih, Gx * Ex);
  k_cvt<<<512, 256, 0, stream>>>(wihb, wih + Gx * Ex, Gx * Ex);
  k_bias<<<4, 256, 0, stream>>>(bihf, bhhf, bihb, bhhb, bcat);
  k_scales<<<2048, 64, 0, stream>>>(whhf, whhb, wsc);
  k_pack_i8<<<128, 256, 0, stream>>>(whhf, whhb, wsc, wq);
  k_vproj<<<1008, 256, 0, stream>>>(embbf, wih, bcat, vp);
  k_vq<<<(2 * Vx + 7) / 8, 512, 0, stream>>>(vp, scg);
  k_rnn<<<256, 512, 0, stream>>>(wq, wsc, (const char*)vp, scg, input, target, gath);
  k_out<<<256, 64, 0, stream>>>(gath, wout, bout, out);
}

// Round 11
// 629.960 us; speedup vs baseline: 1.0338x; 1.0338x over previous
//
#include <hip/hip_runtime.h>
#include <hip/hip_bf16.h>

#define Bx 256
#define Tx 512
#define Ex 768
#define Hx 256
#define Gx 1024
#define Vx 7987

typedef unsigned short u16;
typedef unsigned int u32;
typedef __bf16 bf16;
typedef bf16 bf16x8 __attribute__((ext_vector_type(8)));
typedef u16 u16x8 __attribute__((ext_vector_type(8)));
typedef float f32x4 __attribute__((ext_vector_type(4)));
typedef int i32x4 __attribute__((ext_vector_type(4)));

__device__ __forceinline__ u16 f2bf(float f) {
  union { float f; u32 u; } x; x.f = f;
  u32 r = x.u + 0x7fffu + ((x.u >> 16) & 1u);
  return (u16)(r >> 16);
}
__device__ __forceinline__ float bf2f(u16 b) {
  union { u32 u; float f; } x; x.u = ((u32)b) << 16;
  return x.f;
}
__device__ __forceinline__ void gload16(const void* g, void* l) {
  __builtin_amdgcn_global_load_lds((const __attribute__((address_space(1))) u32*)g,
                                   (__attribute__((address_space(3))) u32*)l, 16, 0, 0);
}
__device__ __forceinline__ float sigf(float x) {
  return __builtin_amdgcn_rcpf(1.f + __builtin_amdgcn_exp2f(x * -1.442695041f));
}
// barrier draining LDS ops only; global loads stay in flight
__device__ __forceinline__ void bar_ds() {
  __builtin_amdgcn_sched_barrier(0);
  asm volatile("s_waitcnt lgkmcnt(0)" ::: "memory");
  __builtin_amdgcn_s_barrier();
  __builtin_amdgcn_sched_barrier(0);
}
#define WAITV(N) { asm volatile("s_waitcnt vmcnt(" #N ")"); __builtin_amdgcn_sched_barrier(0); }

__device__ __forceinline__ void gld2(int2& d, const char* base, u32 voff) {
  asm volatile("global_load_dwordx2 %0, %1, %2" : "=&v"(d) : "v"(voff), "s"(base));
}
// i8 MFMA, K=64: A = h (VGPR), B = weights pinned in AGPR
__device__ __forceinline__ void mfma_i8(i32x4& d, i32x4 a, i32x4 b) {
  asm volatile("v_mfma_i32_16x16x64_i8 %0, %1, %2, %0" : "+v"(d) : "v"(a), "a"(b));
}

// ---------------- conversion / packing kernels ----------------

__global__ void k_cvt(const float* __restrict__ src, u16* __restrict__ dst, int n) {
  int i = blockIdx.x * blockDim.x + threadIdx.x;
  int st = gridDim.x * blockDim.x;
  for (; i < n; i += st) dst[i] = f2bf(src[i]);
}

__global__ void k_bias(const float* __restrict__ bihf, const float* __restrict__ bhhf,
                       const float* __restrict__ bihb, const float* __restrict__ bhhb,
                       float* __restrict__ bcat) {
  int i = blockIdx.x * blockDim.x + threadIdx.x;
  if (i < Gx) { bcat[i] = bihf[i] + bhhf[i]; bcat[Gx + i] = bihb[i] + bhhb[i]; }
}

// per-output-row absmax scale: s[row] = max|w_hh[row,:]| / 127
__global__ void k_scales(const float* __restrict__ wf, const float* __restrict__ wb,
                         float* __restrict__ s) {
  int row = blockIdx.x;  // 0..2047 (dir*1024 + n)
  const float* w = (row < Gx) ? (wf + (size_t)row * Hx) : (wb + (size_t)(row - Gx) * Hx);
  int l = threadIdx.x;
  float m = 0.f;
  for (int j = l; j < Hx; j += 64) m = fmaxf(m, fabsf(w[j]));
#pragma unroll
  for (int off = 32; off; off >>= 1) m = fmaxf(m, __shfl_down(m, off));
  if (l == 0) s[row] = fmaxf(m, 1e-20f) * (1.f / 127.f);
}

// pack w_hh -> i8 fragment-linear for v_mfma_i32_16x16x64_i8 B-operand:
// pk[(((dir*4+kc)*64 + nb)*64 + lane)*16 + j] = q(w[dir][n=nb*16+(lane&15)][k=kc*64+(lane>>4)*16+j])
__global__ void k_pack_i8(const float* __restrict__ wf, const float* __restrict__ wb,
                          const float* __restrict__ s, char* __restrict__ pk) {
  int i = blockIdx.x * 256 + threadIdx.x;  // 32768 packers x 16 B
  int lane = i & 63, nb = (i >> 6) & 63, kc = (i >> 12) & 3, dir = (i >> 14) & 1;
  int n = nb * 16 + (lane & 15);
  int k0 = kc * 64 + ((lane >> 4) << 4);
  const float* w = dir ? wb : wf;
  float inv = 1.f / s[dir * Gx + n];
  int dw[4];
#pragma unroll
  for (int d4 = 0; d4 < 4; ++d4) {
    int v = 0;
#pragma unroll
    for (int j = 0; j < 4; ++j) {
      int q = (int)rintf(w[(size_t)n * Hx + k0 + d4 * 4 + j] * inv);
      v |= (q & 255) << (8 * j);
    }
    dw[d4] = v;
  }
  *(int4*)(pk + (size_t)i * 16) = make_int4(dw[0], dw[1], dw[2], dw[3]);
}

// ---------------- vocab projection GEMM (runs ONCE, bf16) ----------------
// vp[(tok*2 + dir)*1024 + (w*16 + u)*8 + g*2 + fc]
__global__ __launch_bounds__(256) void k_vproj(
    const u16* __restrict__ embbf, const u16* __restrict__ wih,
    const float* __restrict__ bcat, u16* __restrict__ vp) {
  __shared__ u16 sA[128 * 64];
  __shared__ u16 sB[128 * 64];
  const int tid = threadIdx.x;
  const int l = tid & 63, w = tid >> 6;
  const int bx = blockIdx.x & 15, by = blockIdx.x >> 4;  // by: 0..62
  const int wm = w >> 1, wn = w & 1;
  const int lr = l >> 3, lc = l & 7;

  f32x4 acc[4][4];
#pragma unroll
  for (int a = 0; a < 4; ++a)
#pragma unroll
    for (int b = 0; b < 4; ++b) acc[a][b] = f32x4{0.f, 0.f, 0.f, 0.f};

  size_t asrc[4], bsrc[4];
#pragma unroll
  for (int j = 0; j < 4; ++j) {
    int row = j * 32 + w * 8 + lr;
    int m = by * 128 + row;
    int er = (m < Vx) ? m : 0;
    asrc[j] = (size_t)er * (Ex * 2) + (size_t)((lc * 16) ^ ((row & 7) << 4));
    bsrc[j] = (size_t)(bx * 128 + row) * (Ex * 2) + (size_t)((lc * 16) ^ ((row & 7) << 4));
  }

  for (int kt = 0; kt < 12; ++kt) {
    const char* ebase = (const char*)embbf + (size_t)kt * 128;
    const char* wbase = (const char*)wih + (size_t)kt * 128;
#pragma unroll
    for (int j = 0; j < 4; ++j) {
      gload16(ebase + asrc[j], (char*)sA + (j * 32 + w * 8) * 128);
      gload16(wbase + bsrc[j], (char*)sB + (j * 32 + w * 8) * 128);
    }
    __syncthreads();
#pragma unroll
    for (int kk = 0; kk < 2; ++kk) {
      int kb = kk * 64 + ((l >> 4) * 16);
      bf16x8 av[4], bv[4];
#pragma unroll
      for (int f = 0; f < 4; ++f) {
        int r = wm * 64 + f * 16 + (l & 15);
        av[f] = *(const bf16x8*)((const char*)sA + r * 128 + (kb ^ ((r & 7) << 4)));
      }
#pragma unroll
      for (int f = 0; f < 4; ++f) {
        int n = wn * 64 + f * 16 + (l & 15);
        bv[f] = *(const bf16x8*)((const char*)sB + n * 128 + (kb ^ ((n & 7) << 4)));
      }
#pragma unroll
      for (int fm = 0; fm < 4; ++fm)
#pragma unroll
        for (int fn = 0; fn < 4; ++fn)
          acc[fm][fn] = __builtin_amdgcn_mfma_f32_16x16x32_bf16(av[fm], bv[fn], acc[fm][fn], 0, 0, 0);
    }
    __syncthreads();
  }
#pragma unroll
  for (int fn = 0; fn < 4; ++fn) {
    int col = bx * 128 + wn * 64 + fn * 16 + (l & 15);
    int dirc = col >> 10, c10 = col & 1023;
    int gq = c10 >> 8, wq = (c10 >> 5) & 7, fcq = (c10 >> 4) & 1, uq = c10 & 15;
    int pos = (wq * 16 + uq) * 8 + gq * 2 + fcq;
    float bias = bcat[col];
#pragma unroll
    for (int fm = 0; fm < 4; ++fm) {
      int m0 = by * 128 + wm * 64 + fm * 16 + ((l >> 4) << 2);
#pragma unroll
      for (int r = 0; r < 4; ++r)
        vp[((size_t)(m0 + r) * 2 + dirc) * 1024 + pos] = f2bf(acc[fm][fn][r] + bias);
    }
  }
}

// ---------------- vp -> i8 quantize, IN PLACE (race-free chunked) ----------------
// Block b owns rows [b*8, b*8+8). Reads all 8 rows (bf16) to regs, syncs, writes
// 1KB i8 rows into the chunk's first half: row r at (r>>3)*16384 + (r&7)*1024.
__global__ __launch_bounds__(512) void k_vq(u16* __restrict__ vp, float* __restrict__ scg) {
  const int tid = threadIdx.x;
  const int l = tid & 63;
  int row = blockIdx.x * 8 + (tid >> 6);
  bool valid = row < 2 * Vx;
  int rr = valid ? row : 2 * Vx - 1;
  const u16* src = vp + (size_t)rr * 1024;
  float v[16];
  float m = 0.f;
#pragma unroll
  for (int j = 0; j < 16; ++j) {
    v[j] = bf2f(src[l * 16 + j]);
    m = fmaxf(m, fabsf(v[j]));
  }
#pragma unroll
  for (int off = 32; off; off >>= 1) m = fmaxf(m, __shfl_xor(m, off));
  float sc = fmaxf(m, 1e-20f) * (1.f / 127.f);
  float inv = 1.f / sc;
  if (valid && l == 0) scg[row] = sc;
  __syncthreads();  // all reads of the 16KB chunk done before any write
  if (valid) {
    int dw[4];
#pragma unroll
    for (int d4 = 0; d4 < 4; ++d4) {
      int wv = 0;
#pragma unroll
      for (int j = 0; j < 4; ++j) {
        int qv = (int)rintf(v[d4 * 4 + j] * inv);
        wv |= (qv & 255) << (8 * j);
      }
      dw[d4] = wv;
    }
    char* dst = (char*)vp + (size_t)blockIdx.x * 16384 + (size_t)(row & 7) * 1024;
    *(int4*)(dst + l * 16) = make_int4(dw[0], dw[1], dw[2], dw[3]);
  }
}

// ---------------- recurrence: ONE launch, all 512 steps ----------------
// 128 blocks = 2 dirs x 64 slices (4 rows). 8 waves/block (measured-best blocking).
// w_hh AGPR-resident (i8). h: rotated-replica frag-linear LDS, dbuf: A-row 4m+jj
// holds real row (m+jj)&3 -> lane's acc[.][0] is its own row q. c: registers.
// x-proj: i8 vpq gather (8 B/lane) + per-(tok,dir) scale from LDS table.
// Pipeline: ONE WAITV(0) per step-pair (counting-proof), loads issued at pair top.
#define STEPI(T, RB, WB, XC, SC) {                                            \
  i32x4 acc[8];                                                               \
  _Pragma("unroll") for (int nt = 0; nt < 8; ++nt) acc[nt] = i32x4{0, 0, 0, 0}; \
  _Pragma("unroll") for (int kc = 0; kc < 4; ++kc) {                          \
    i32x4 a = *(const i32x4*)((RB) + kc * 1024 + aoff);                       \
    _Pragma("unroll") for (int nt = 0; nt < 8; ++nt)                          \
      mfma_i8(acc[nt], a, wres[kc][nt]);                                      \
  }                                                                           \
  /* acc-independent: unpack x-projection while MFMA pipe drains */           \
  float xf[8];                                                                \
  _Pragma("unroll") for (int j = 0; j < 8; ++j) {                             \
    int wd = (j < 4) ? (XC).x : (XC).y;                                       \
    xf[j] = (float)((wd << (24 - 8 * (j & 3))) >> 24) * (SC);                 \
  }                                                                           \
  asm volatile("s_nop 7\n\ts_nop 7");                                         \
  float ga[2][4];                                                             \
  _Pragma("unroll") for (int fc = 0; fc < 2; ++fc)                            \
    _Pragma("unroll") for (int g = 0; g < 4; ++g)                             \
      ga[fc][g] = (float)acc[g * 2 + fc][0] * qs[g * 2 + fc] + xf[g * 2 + fc]; \
  _Pragma("unroll") for (int fc = 0; fc < 2; ++fc) {                          \
    float si = sigf(ga[fc][0]);                                               \
    float sf = sigf(ga[fc][1]);                                               \
    float tv = 2.f * sigf(2.f * ga[fc][2]) - 1.f;                             \
    float so = sigf(ga[fc][3]);                                               \
    float cn = sf * creg[fc] + si * tv;                                       \
    float hn = so * (2.f * sigf(2.f * cn) - 1.f);                             \
    creg[fc] = cn;                                                            \
    if ((T) == tgt)                                                           \
      gath[(size_t)(b0 + q) * 512 + dir * 256 + w * 32 + fc * 16 + c] = hn;   \
    int qh = (int)rintf(hn * 127.f);                                          \
    _Pragma("unroll") for (int m = 0; m < 4; ++m)                             \
      *((WB) + wb_base + fc * 256 + m * 64 + (((q - m) & 3) << 4)) = (char)qh; \
  }                                                                           \
  bar_ds();                                                                   \
}

__global__ __launch_bounds__(512, 2) void k_rnn(
    const char* __restrict__ wq, const float* __restrict__ wsc,
    const char* __restrict__ vpq, const float* __restrict__ scg,
    const int* __restrict__ input, const int* __restrict__ target,
    float* __restrict__ gath) {
  __shared__ __align__(16) char shd[2][4096];  // h i8 rotated-replica, dbuf
  __shared__ int stok[4 * 520];                // tokens [4 rows][520] (tail-padded)
  __shared__ float ssc[Vx];                    // per-token vp scale (own dir)
  const int tid = threadIdx.x;
  const int l = tid & 63, w = tid >> 6;
  const int q = l >> 4, c = l & 15;
  const int dir = blockIdx.x >> 6, slice = blockIdx.x & 63;
  const int b0 = slice * 4;
  const char* wqd = wq + (size_t)dir * 262144;

  // all w_hh -> AGPR: 4 kc x 8 nt x 16 B = 512 B/lane = 128 AGPRs
  i32x4 wres[4][8];
#pragma unroll
  for (int kc = 0; kc < 4; ++kc)
#pragma unroll
    for (int nt = 0; nt < 8; ++nt) {
      int nb = (nt >> 1) * 16 + w * 2 + (nt & 1);
      wres[kc][nt] = *(const i32x4*)(wqd + ((size_t)(kc * 64 + nb) * 64 + l) * 16);
    }
  float qs[8];
#pragma unroll
  for (int nt = 0; nt < 8; ++nt)
    qs[nt] = wsc[dir * Gx + (nt >> 1) * 256 + w * 32 + (nt & 1) * 16 + c] * (1.f / 127.f);

  // tokens (padded) + scale table -> LDS; zero both h buffers
  for (int i = tid; i < 4 * 520; i += 512) {
    int r = i / 520, t = i - r * 520;
    stok[i] = input[(b0 + r) * Tx + (t < Tx ? t : Tx - 1)];
  }
  for (int i = tid; i < Vx; i += 512) ssc[i] = scg[i * 2 + dir];
  for (int i = tid; i < 2048; i += 512) ((int*)shd)[i] = 0;

  float creg[2] = {0.f, 0.f};
  const int tgt = target[b0 + q];
  const u32 go2 = (u32)((w * 16 + c) * 8);

  const int aoff = (q << 8) + (c << 4);                    // A-frag read offset
  const int wb_base = (w >> 1) * 1024 + (w & 1) * 512 + c; // h write base
  const char* rb0 = &shd[0][0];
  const char* rb1 = &shd[1][0];
  char* wb0 = &shd[0][0];
  char* wb1 = &shd[1][0];

  __syncthreads();
  asm volatile("s_waitcnt vmcnt(0)" ::: "memory");
  __builtin_amdgcn_sched_barrier(0);

  // prologue: tokens t=0,1; scales; issue both loads
  int tk0 = stok[q * 520 + 0];
  int tk1 = stok[q * 520 + 1];
  float scA = ssc[tk0], scB = ssc[tk1];
  int2 xvA, xvB;
  {
    u32 rA = (u32)(tk0 * 2 + dir), rB = (u32)(tk1 * 2 + dir);
    gld2(xvA, vpq, ((rA >> 3) << 14) + ((rA & 7) << 10) + go2);
    gld2(xvB, vpq, ((rB >> 3) << 14) + ((rB & 7) << 10) + go2);
  }

#pragma unroll 1
  for (int t = 0; t < Tx; t += 2) {
    WAITV(0);  // xvA(t), xvB(t+1) landed; ALL other VMEM drained (counting-proof)
    int2 xcA = xvA, xcB = xvB;
    float cA = scA, cB = scB;
    int ta = stok[q * 520 + t + 2];
    int tb = stok[q * 520 + t + 3];
    scA = ssc[ta];
    scB = ssc[tb];
    {
      u32 rA = (u32)(ta * 2 + dir), rB = (u32)(tb * 2 + dir);
      gld2(xvA, vpq, ((rA >> 3) << 14) + ((rA & 7) << 10) + go2);  // full-pair window
      gld2(xvB, vpq, ((rB >> 3) << 14) + ((rB & 7) << 10) + go2);
    }
    STEPI(t, rb0, wb1, xcA, cA);
    STEPI(t + 1, rb1, wb0, xcB, cB);
  }
}

// ---------------- output head ----------------
__global__ void k_out(const float* __restrict__ gath, const float* __restrict__ wout,
                      const float* __restrict__ bout, float* __restrict__ out) {
  int b = blockIdx.x, l = threadIdx.x;
  float s = 0.f;
  for (int j = l; j < 512; j += 64) s += gath[(size_t)b * 512 + j] * wout[j];
#pragma unroll
  for (int off = 32; off; off >>= 1) s += __shfl_down(s, off);
  if (l == 0) out[b] = 1.f / (1.f + __expf(-(s + bout[0])));
}

extern "C" void kernel_launch(void* const* d_in, const int* in_sizes, int n_in,
                              void* d_out, int out_size, void* d_ws, size_t ws_size,
                              hipStream_t stream) {
  const int* input = (const int*)d_in[0];
  const int* target = (const int*)d_in[1];
  const float* emb  = (const float*)d_in[3];
  const float* wihf = (const float*)d_in[4];
  const float* whhf = (const float*)d_in[5];
  const float* bihf = (const float*)d_in[6];
  const float* bhhf = (const float*)d_in[7];
  const float* wihb = (const float*)d_in[8];
  const float* whhb = (const float*)d_in[9];
  const float* bihb = (const float*)d_in[10];
  const float* bhhb = (const float*)d_in[11];
  const float* wout = (const float*)d_in[12];
  const float* bout = (const float*)d_in[13];
  float* out = (float*)d_out;

  char* ws = (char*)d_ws;
  u16* embbf  = (u16*)(ws + 0);          // 12,268,032 B
  u16* wih    = (u16*)(ws + 12268032);   //  3,145,728 B
  char* wq    = (char*)(ws + 15413760);  //    524,288 B  i8 packed w_hh
  float* wsc  = (float*)(ws + 15938048); //      8,192 B  per-row scales
  float* bcat = (float*)(ws + 15946240); //      8,192 B
  float* gath = (float*)(ws + 15954432); //    524,288 B
  u16* vp     = (u16*)(ws + 16478720);   // 33,030,144 B  bf16 -> quantized in place
  float* scg  = (float*)(ws + 49508864); //     65,536 B  per-(tok,dir) vp scales

  k_cvt<<<1024, 256, 0, stream>>>(emb, embbf, Vx * Ex);
  k_cvt<<<512, 256, 0, stream>>>(wihf, wih, Gx * Ex);
  k_cvt<<<512, 256, 0, stream>>>(wihb, wih + Gx * Ex, Gx * Ex);
  k_bias<<<4, 256, 0, stream>>>(bihf, bhhf, bihb, bhhb, bcat);
  k_scales<<<2048, 64, 0, stream>>>(whhf, whhb, wsc);
  k_pack_i8<<<128, 256, 0, stream>>>(whhf, whhb, wsc, wq);
  k_vproj<<<1008, 256, 0, stream>>>(embbf, wih, bcat, vp);
  k_vq<<<(2 * Vx + 7) / 8, 512, 0, stream>>>(vp, scg);
  k_rnn<<<128, 512, 0, stream>>>(wq, wsc, (const char*)vp, scg, input, target, gath);
  k_out<<<256, 64, 0, stream>>>(gath, wout, bout, out);
}

// Round 14
// 488.900 us; speedup vs baseline: 1.3320x; 1.2885x over previous
//
#include <hip/hip_runtime.h>
#include <hip/hip_bf16.h>

#define Bx 256
#define Tx 512
#define Ex 768
#define Hx 256
#define Gx 1024
#define Vx 7987

typedef unsigned short u16;
typedef unsigned int u32;
typedef __bf16 bf16;
typedef bf16 bf16x8 __attribute__((ext_vector_type(8)));
typedef float f32x4 __attribute__((ext_vector_type(4)));
typedef int i32x4 __attribute__((ext_vector_type(4)));

__device__ __forceinline__ u16 f2bf(float f) {
  union { float f; u32 u; } x; x.f = f;
  u32 r = x.u + 0x7fffu + ((x.u >> 16) & 1u);
  return (u16)(r >> 16);
}
__device__ __forceinline__ float bf2f(u16 b) {
  union { u32 u; float f; } x; x.u = ((u32)b) << 16;
  return x.f;
}
__device__ __forceinline__ float asf(u32 u) {
  union { u32 u; float f; } x; x.u = u; return x.f;
}
__device__ __forceinline__ void gload16(const void* g, void* l) {
  __builtin_amdgcn_global_load_lds((const __attribute__((address_space(1))) u32*)g,
                                   (__attribute__((address_space(3))) u32*)l, 16, 0, 0);
}
__device__ __forceinline__ float sigf(float x) {
  return __builtin_amdgcn_rcpf(1.f + __builtin_amdgcn_exp2f(x * -1.442695041f));
}
// barrier draining LDS ops only; global loads stay in flight
__device__ __forceinline__ void bar_ds() {
  __builtin_amdgcn_sched_barrier(0);
  asm volatile("s_waitcnt lgkmcnt(0)" ::: "memory");
  __builtin_amdgcn_s_barrier();
  __builtin_amdgcn_sched_barrier(0);
}
#define WAITV(N) { asm volatile("s_waitcnt vmcnt(" #N ")"); __builtin_amdgcn_sched_barrier(0); }

// virtual-register global load (R9-R11-proven); correct as long as no spill,
// which the register budget guarantees (see k_rnn header comment).
__device__ __forceinline__ void gld2(int2& d, const char* base, u32 voff) {
  asm volatile("global_load_dwordx2 %0, %1, %2" : "=&v"(d) : "v"(voff), "s"(base));
}
// i8 MFMA, K=64: B pinned in AGPR. Accumulating form: D=C tied ("+v").
__device__ __forceinline__ void mfma_i8(i32x4& d, i32x4 a, i32x4 b) {
  asm volatile("v_mfma_i32_16x16x64_i8 %0, %1, %2, %0" : "+v"(d) : "v"(a), "a"(b));
}
// zero-C form: inline-constant C, EARLY-CLOBBER dest (D must not overlap A/B).
__device__ __forceinline__ void mfma_i8z(i32x4& d, i32x4 a, i32x4 b) {
  asm volatile("v_mfma_i32_16x16x64_i8 %0, %1, %2, 0" : "=&v"(d) : "v"(a), "a"(b));
}

// ---------------- conversion / packing kernels ----------------

__global__ void k_cvt(const float* __restrict__ src, u16* __restrict__ dst, int n) {
  int i = blockIdx.x * blockDim.x + threadIdx.x;
  int st = gridDim.x * blockDim.x;
  for (; i < n; i += st) dst[i] = f2bf(src[i]);
}

__global__ void k_bias(const float* __restrict__ bihf, const float* __restrict__ bhhf,
                       const float* __restrict__ bihb, const float* __restrict__ bhhb,
                       float* __restrict__ bcat) {
  int i = blockIdx.x * blockDim.x + threadIdx.x;
  if (i < Gx) { bcat[i] = bihf[i] + bhhf[i]; bcat[Gx + i] = bihb[i] + bhhb[i]; }
}

// per-output-row absmax scale: s[row] = max|w_hh[row,:]| / 127
__global__ void k_scales(const float* __restrict__ wf, const float* __restrict__ wb,
                         float* __restrict__ s) {
  int row = blockIdx.x;  // 0..2047 (dir*1024 + n)
  const float* w = (row < Gx) ? (wf + (size_t)row * Hx) : (wb + (size_t)(row - Gx) * Hx);
  int l = threadIdx.x;
  float m = 0.f;
  for (int j = l; j < Hx; j += 64) m = fmaxf(m, fabsf(w[j]));
#pragma unroll
  for (int off = 32; off; off >>= 1) m = fmaxf(m, __shfl_down(m, off));
  if (l == 0) s[row] = fmaxf(m, 1e-20f) * (1.f / 127.f);
}

// pack w_hh -> i8 fragment-linear for v_mfma_i32_16x16x64_i8 B-operand:
// pk[(((dir*4+kc)*64 + nb)*64 + lane)*16 + j] = q(w[dir][n=nb*16+(lane&15)][k=kc*64+(lane>>4)*16+j])
__global__ void k_pack_i8(const float* __restrict__ wf, const float* __restrict__ wb,
                          const float* __restrict__ s, char* __restrict__ pk) {
  int i = blockIdx.x * 256 + threadIdx.x;  // 32768 packers x 16 B
  int lane = i & 63, nb = (i >> 6) & 63, kc = (i >> 12) & 3, dir = (i >> 14) & 1;
  int n = nb * 16 + (lane & 15);
  int k0 = kc * 64 + ((lane >> 4) << 4);
  const float* w = dir ? wb : wf;
  float inv = 1.f / s[dir * Gx + n];
  int dw[4];
#pragma unroll
  for (int d4 = 0; d4 < 4; ++d4) {
    int v = 0;
#pragma unroll
    for (int j = 0; j < 4; ++j) {
      int q = (int)rintf(w[(size_t)n * Hx + k0 + d4 * 4 + j] * inv);
      v |= (q & 255) << (8 * j);
    }
    dw[d4] = v;
  }
  *(int4*)(pk + (size_t)i * 16) = make_int4(dw[0], dw[1], dw[2], dw[3]);
}

// ---------------- vocab projection GEMM (runs ONCE, bf16) ----------------
// vp[(tok*2 + dir)*1024 + u*4 + g]  (u = unit 0..255, g = gate) -> a lane's 4
// gates for its unit are one contiguous 8-byte dwordx2.
__global__ __launch_bounds__(256) void k_vproj(
    const u16* __restrict__ embbf, const u16* __restrict__ wih,
    const float* __restrict__ bcat, u16* __restrict__ vp) {
  __shared__ u16 sA[128 * 64];
  __shared__ u16 sB[128 * 64];
  const int tid = threadIdx.x;
  const int l = tid & 63, w = tid >> 6;
  const int bx = blockIdx.x & 15, by = blockIdx.x >> 4;  // by: 0..62
  const int wm = w >> 1, wn = w & 1;
  const int lr = l >> 3, lc = l & 7;

  f32x4 acc[4][4];
#pragma unroll
  for (int a = 0; a < 4; ++a)
#pragma unroll
    for (int b = 0; b < 4; ++b) acc[a][b] = f32x4{0.f, 0.f, 0.f, 0.f};

  size_t asrc[4], bsrc[4];
#pragma unroll
  for (int j = 0; j < 4; ++j) {
    int row = j * 32 + w * 8 + lr;
    int m = by * 128 + row;
    int er = (m < Vx) ? m : 0;
    asrc[j] = (size_t)er * (Ex * 2) + (size_t)((lc * 16) ^ ((row & 7) << 4));
    bsrc[j] = (size_t)(bx * 128 + row) * (Ex * 2) + (size_t)((lc * 16) ^ ((row & 7) << 4));
  }

  for (int kt = 0; kt < 12; ++kt) {
    const char* ebase = (const char*)embbf + (size_t)kt * 128;
    const char* wbase = (const char*)wih + (size_t)kt * 128;
#pragma unroll
    for (int j = 0; j < 4; ++j) {
      gload16(ebase + asrc[j], (char*)sA + (j * 32 + w * 8) * 128);
      gload16(wbase + bsrc[j], (char*)sB + (j * 32 + w * 8) * 128);
    }
    __syncthreads();
#pragma unroll
    for (int kk = 0; kk < 2; ++kk) {
      int kb = kk * 64 + ((l >> 4) * 16);
      bf16x8 av[4], bv[4];
#pragma unroll
      for (int f = 0; f < 4; ++f) {
        int r = wm * 64 + f * 16 + (l & 15);
        av[f] = *(const bf16x8*)((const char*)sA + r * 128 + (kb ^ ((r & 7) << 4)));
      }
#pragma unroll
      for (int f = 0; f < 4; ++f) {
        int n = wn * 64 + f * 16 + (l & 15);
        bv[f] = *(const bf16x8*)((const char*)sB + n * 128 + (kb ^ ((n & 7) << 4)));
      }
#pragma unroll
      for (int fm = 0; fm < 4; ++fm)
#pragma unroll
        for (int fn = 0; fn < 4; ++fn)
          acc[fm][fn] = __builtin_amdgcn_mfma_f32_16x16x32_bf16(av[fm], bv[fn], acc[fm][fn], 0, 0, 0);
    }
    __syncthreads();
  }
#pragma unroll
  for (int fn = 0; fn < 4; ++fn) {
    int col = bx * 128 + wn * 64 + fn * 16 + (l & 15);
    int dirc = col >> 10, c10 = col & 1023;
    int gq = c10 >> 8, uq = c10 & 255;
    int pos = uq * 4 + gq;
    float bias = bcat[col];
#pragma unroll
    for (int fm = 0; fm < 4; ++fm) {
      int m0 = by * 128 + wm * 64 + fm * 16 + ((l >> 4) << 2);
#pragma unroll
      for (int r = 0; r < 4; ++r)
        vp[((size_t)(m0 + r) * 2 + dirc) * 1024 + pos] = f2bf(acc[fm][fn][r] + bias);
    }
  }
}

// ---------------- recurrence: ONE launch, all 512 steps ----------------
// 128 blocks = 2 dirs x 64 slices (4 rows). 16 waves x 64 = 1024 threads,
// launch_bounds(1024,4): 128 unified regs/wave = 64 AGPR (weights) + <=64 VGPR.
// VGPR live-set budget: ~17 persistent + 16 A-frags + 16 acc + 8 xv/xc ~ 57-60
// -> no spill -> virtual-reg asm loads are safe (R9-R11-proven pattern).
// Wave w owns nb = g*16+w per gate -> wres[4][4]. Lane: 1 h (row q, u=w*16+c).
// Rotated-replica h LDS (M-row 4m+jj holds real row (m+jj)&3 -> acc_g[0] is
// the lane's own row q). c-state in reg. ONE WAITV(0) per step-pair.
#define STEPB(T, RB, WB, XC) {                                               \
  i32x4 a0 = *(const i32x4*)(RB);                                            \
  i32x4 a1 = *(const i32x4*)((RB) + 1024);                                   \
  i32x4 a2 = *(const i32x4*)((RB) + 2048);                                   \
  i32x4 a3 = *(const i32x4*)((RB) + 3072);                                   \
  i32x4 acc0, acc1, acc2, acc3;                                              \
  mfma_i8z(acc0, a0, wres[0][0]);                                            \
  mfma_i8z(acc1, a0, wres[0][1]);                                            \
  mfma_i8z(acc2, a0, wres[0][2]);                                            \
  mfma_i8z(acc3, a0, wres[0][3]);                                            \
  mfma_i8(acc0, a1, wres[1][0]);                                             \
  mfma_i8(acc1, a1, wres[1][1]);                                             \
  mfma_i8(acc2, a1, wres[1][2]);                                             \
  mfma_i8(acc3, a1, wres[1][3]);                                             \
  mfma_i8(acc0, a2, wres[2][0]);                                             \
  mfma_i8(acc1, a2, wres[2][1]);                                             \
  mfma_i8(acc2, a2, wres[2][2]);                                             \
  mfma_i8(acc3, a2, wres[2][3]);                                             \
  mfma_i8(acc0, a3, wres[3][0]);                                             \
  mfma_i8(acc1, a3, wres[3][1]);                                             \
  mfma_i8(acc2, a3, wres[3][2]);                                             \
  mfma_i8(acc3, a3, wres[3][3]);                                             \
  asm volatile("s_nop 7\n\ts_nop 7");                                        \
  float g0 = (float)acc0[0] * qs[0] + asf(((u32)(XC).x) << 16);              \
  float g1 = (float)acc1[0] * qs[1] + asf(((u32)(XC).x) & 0xffff0000u);      \
  float g2 = (float)acc2[0] * qs[2] + asf(((u32)(XC).y) << 16);              \
  float g3 = (float)acc3[0] * qs[3] + asf(((u32)(XC).y) & 0xffff0000u);      \
  float si = sigf(g0);                                                       \
  float sf = sigf(g1);                                                       \
  float tv = 2.f * sigf(2.f * g2) - 1.f;                                     \
  float so = sigf(g3);                                                       \
  float cn = sf * creg + si * tv;                                            \
  float hn = so * (2.f * sigf(2.f * cn) - 1.f);                              \
  creg = cn;                                                                 \
  if ((T) == tgt) gath[(size_t)(b0 + q) * 512 + dir * 256 + w * 16 + c] = hn; \
  int qh = (int)rintf(hn * 127.f);                                           \
  *((WB) + wp0) = (char)qh;                                                  \
  *((WB) + wp1) = (char)qh;                                                  \
  *((WB) + wp2) = (char)qh;                                                  \
  *((WB) + wp3) = (char)qh;                                                  \
  bar_ds();                                                                  \
}

__global__ __launch_bounds__(1024, 4) void k_rnn(
    const char* __restrict__ wq, const float* __restrict__ wsc,
    const char* __restrict__ vp, const int* __restrict__ input,
    const int* __restrict__ target, float* __restrict__ gath) {
  __shared__ __align__(16) char shd[2][4096];  // h i8 rotated-replica, dbuf
  __shared__ int stok[4 * 520];                // tokens [4 rows][520] padded
  const int tid = threadIdx.x;
  const int l = tid & 63, w = tid >> 6;        // w: 0..15
  const int q = l >> 4, c = l & 15;
  const int dir = blockIdx.x >> 6, slice = blockIdx.x & 63;
  const int b0 = slice * 4;
  const char* wqd = wq + (size_t)dir * 262144;

  // w_hh -> AGPR: wave w owns nb = g*16 + w; 4 kc x 4 g x 16 B = 64 AGPRs
  i32x4 wres[4][4];
#pragma unroll
  for (int kc = 0; kc < 4; ++kc)
#pragma unroll
    for (int g = 0; g < 4; ++g)
      wres[kc][g] = *(const i32x4*)(wqd + ((size_t)(kc * 64 + g * 16 + w) * 64 + l) * 16);
  float qs[4];
#pragma unroll
  for (int g = 0; g < 4; ++g)
    qs[g] = wsc[dir * Gx + g * 256 + w * 16 + c] * (1.f / 127.f);

  // tokens (padded) -> LDS; zero both h buffers
  for (int i = tid; i < 4 * 520; i += 1024) {
    int r = i / 520, t = i - r * 520;
    stok[i] = input[(b0 + r) * Tx + (t < Tx ? t : Tx - 1)];
  }
  for (int i = tid; i < 2048; i += 1024) ((int*)shd)[i] = 0;

  float creg = 0.f;
  const int tgt = target[b0 + q];
  const u32 go2 = (u32)(dir * 2048 + (w * 16 + c) * 8);

  // A-frag read: buf[kc][kq=q][row=c][16B]; pointers pre-offset by aoff
  const int aoff = (q << 8) + (c << 4);
  const char* rb0 = &shd[0][0] + aoff;
  const char* rb1 = &shd[1][0] + aoff;
  // h write: unit u=w*16+c -> kc=w>>2, kq=w&3; replica rows p = 4m+((q-m)&3)
  const int wbs = (w >> 2) * 1024 + (w & 3) * 256 + c;
  char* wb0 = &shd[0][0] + wbs;
  char* wb1 = &shd[1][0] + wbs;
  const int wp0 = ((q - 0) & 3) << 4;
  const int wp1 = 64 + (((q - 1) & 3) << 4);
  const int wp2 = 128 + (((q - 2) & 3) << 4);
  const int wp3 = 192 + (((q - 3) & 3) << 4);
  const int* stq = stok + q * 520;

  __syncthreads();
  asm volatile("s_waitcnt vmcnt(0)" ::: "memory");
  __builtin_amdgcn_sched_barrier(0);

  // prologue: issue xv(t=0), xv(t=1) into virtual regs
  int2 xvA, xvB;
  gld2(xvA, vp, (u32)stq[0] * 4096 + go2);
  gld2(xvB, vp, (u32)stq[1] * 4096 + go2);

#pragma unroll 1
  for (int t = 0; t < Tx; t += 2) {
    WAITV(0);  // xvA(t), xvB(t+1) landed; ALL other VMEM drained (counting-proof)
    int2 xcA = xvA, xcB = xvB;
    gld2(xvA, vp, (u32)stq[t + 2] * 4096 + go2);  // ~2-step window
    gld2(xvB, vp, (u32)stq[t + 3] * 4096 + go2);
    STEPB(t, rb0, wb1, xcA);
    STEPB(t + 1, rb1, wb0, xcB);
  }
}

// ---------------- output head ----------------
__global__ void k_out(const float* __restrict__ gath, const float* __restrict__ wout,
                      const float* __restrict__ bout, float* __restrict__ out) {
  int b = blockIdx.x, l = threadIdx.x;
  float s = 0.f;
  for (int j = l; j < 512; j += 64) s += gath[(size_t)b * 512 + j] * wout[j];
#pragma unroll
  for (int off = 32; off; off >>= 1) s += __shfl_down(s, off);
  if (l == 0) out[b] = 1.f / (1.f + __expf(-(s + bout[0])));
}

extern "C" void kernel_launch(void* const* d_in, const int* in_sizes, int n_in,
                              void* d_out, int out_size, void* d_ws, size_t ws_size,
                              hipStream_t stream) {
  const int* input = (const int*)d_in[0];
  const int* target = (const int*)d_in[1];
  const float* emb  = (const float*)d_in[3];
  const float* wihf = (const float*)d_in[4];
  const float* whhf = (const float*)d_in[5];
  const float* bihf = (const float*)d_in[6];
  const float* bhhf = (const float*)d_in[7];
  const float* wihb = (const float*)d_in[8];
  const float* whhb = (const float*)d_in[9];
  const float* bihb = (const float*)d_in[10];
  const float* bhhb = (const float*)d_in[11];
  const float* wout = (const float*)d_in[12];
  const float* bout = (const float*)d_in[13];
  float* out = (float*)d_out;

  char* ws = (char*)d_ws;
  u16* embbf  = (u16*)(ws + 0);          // 12,268,032 B
  u16* wih    = (u16*)(ws + 12268032);   //  3,145,728 B
  char* wq    = (char*)(ws + 15413760);  //    524,288 B  i8 packed w_hh
  float* wsc  = (float*)(ws + 15938048); //      8,192 B  per-row scales
  float* bcat = (float*)(ws + 15946240); //      8,192 B
  float* gath = (float*)(ws + 15954432); //    524,288 B
  u16* vp     = (u16*)(ws + 16478720);   // 33,030,144 B  bf16 vocab projection

  k_cvt<<<1024, 256, 0, stream>>>(emb, embbf, Vx * Ex);
  k_cvt<<<512, 256, 0, stream>>>(wihf, wih, Gx * Ex);
  k_cvt<<<512, 256, 0, stream>>>(wihb, wih + Gx * Ex, Gx * Ex);
  k_bias<<<4, 256, 0, stream>>>(bihf, bhhf, bihb, bhhb, bcat);
  k_scales<<<2048, 64, 0, stream>>>(whhf, whhb, wsc);
  k_pack_i8<<<128, 256, 0, stream>>>(whhf, whhb, wsc, wq);
  k_vproj<<<1008, 256, 0, stream>>>(embbf, wih, bcat, vp);
  k_rnn<<<128, 1024, 0, stream>>>(wq, wsc, (const char*)vp, input, target, gath);
  k_out<<<256, 64, 0, stream>>>(gath, wout, bout, out);
}